// Round 1
// baseline (7075.923 us; speedup 1.0000x reference)
//
#include <hip/hip_runtime.h>
#include <math.h>

#define NPTS 50000
#define NG   128
#define DD   32
#define FF   64
#define AA   8
#define HINC 1120   // DD + FF + 2*FF*AA
#define EPSV 1e-5f

// ---------------------------------------------------------------- init: segment offsets + zero stats
__global__ __launch_bounds__(256) void k_init(const int* __restrict__ batch,
                                              int* __restrict__ offs,
                                              float* __restrict__ stats) {
    int t = threadIdx.x;
    if (t <= NG) {
        // lower_bound of value t in sorted batch
        int lo = 0, hi = NPTS;
        while (lo < hi) { int mid = (lo + hi) >> 1; if (batch[mid] < t) lo = mid + 1; else hi = mid; }
        offs[t] = lo;
    }
    if (t < 32) stats[t] = 0.f;
}

// ---------------------------------------------------------------- embed: h = tanh(ln(x@Wi+bi))
__global__ __launch_bounds__(256) void k_embed(const float* __restrict__ x,
                                               const float* __restrict__ Wi,
                                               const float* __restrict__ bi,
                                               const float* __restrict__ lw,
                                               const float* __restrict__ lb,
                                               float* __restrict__ h) {
    int n = blockIdx.x * 256 + threadIdx.x;
    if (n >= NPTS) return;
    float x0 = x[n*3+0], x1 = x[n*3+1], x2 = x[n*3+2];
    float v[DD]; float m = 0.f;
    #pragma unroll
    for (int d = 0; d < DD; d++) {
        float t = x0*Wi[d] + x1*Wi[DD+d] + x2*Wi[2*DD+d] + bi[d];
        v[d] = t; m += t;
    }
    m *= (1.f/DD);
    float var = 0.f;
    #pragma unroll
    for (int d = 0; d < DD; d++) { float c = v[d]-m; var += c*c; }
    var *= (1.f/DD);
    float inv = 1.f/sqrtf(var + EPSV);
    #pragma unroll
    for (int d = 0; d < DD; d++) h[(size_t)n*DD + d] = tanhf((v[d]-m)*inv*lw[d] + lb[d]);
}

// ---------------------------------------------------------------- xp = h@Win+bin ; attn = exp(-|xp@Wsc+bsc|)
__global__ __launch_bounds__(256) void k_xp(const float* __restrict__ h,
                                            const float* __restrict__ Win,
                                            const float* __restrict__ bin,
                                            const float* __restrict__ Wsc,
                                            const float* __restrict__ bsc,
                                            float* __restrict__ xp,
                                            float* __restrict__ attn) {
    int n = blockIdx.x * 256 + threadIdx.x;
    if (n >= NPTS) return;
    float hr[DD];
    const float4* h4 = (const float4*)(h + (size_t)n*DD);
    #pragma unroll
    for (int i = 0; i < DD/4; i++) {
        float4 v = h4[i];
        hr[4*i] = v.x; hr[4*i+1] = v.y; hr[4*i+2] = v.z; hr[4*i+3] = v.w;
    }
    float xr[FF];
    #pragma unroll
    for (int f = 0; f < FF; f++) xr[f] = bin[f];
    #pragma unroll
    for (int i = 0; i < DD; i++) {
        float hv = hr[i];
        #pragma unroll
        for (int f = 0; f < FF; f++) xr[f] += hv * Win[i*FF + f];  // uniform idx -> s_load
    }
    #pragma unroll
    for (int a = 0; a < AA; a++) {
        float acc = bsc[a];
        #pragma unroll
        for (int f = 0; f < FF; f++) acc += xr[f] * Wsc[f*AA + a];
        attn[(size_t)n*AA + a] = expf(-fabsf(acc));
    }
    float4* xo = (float4*)(xp + (size_t)n*FF);
    #pragma unroll
    for (int i = 0; i < FF/4; i++) {
        float4 v; v.x = xr[4*i]; v.y = xr[4*i+1]; v.z = xr[4*i+2]; v.w = xr[4*i+3];
        xo[i] = v;
    }
}

// ---------------------------------------------------------------- per-graph agg (mean+max of attn*xp) then aggW = agg @ Wout[96:,:]
__global__ __launch_bounds__(512) void k_agg(const float* __restrict__ xp,
                                             const float* __restrict__ attn,
                                             const int* __restrict__ offs,
                                             const float* __restrict__ Wagg,  // = W_out[j] + 96*DD
                                             float* __restrict__ aggW) {
    int g = blockIdx.x;
    int t = threadIdx.x;           // 512 = AA * FF
    int a = t >> 6, f = t & 63;
    int s = offs[g], e = offs[g+1];
    float sum = 0.f, mx = -INFINITY;
    #pragma unroll 4
    for (int n = s; n < e; n++) {
        float w = attn[(size_t)n*AA + a] * xp[(size_t)n*FF + f];
        sum += w;
        mx = fmaxf(mx, w);
    }
    float cnt = (float)(e - s);
    float mean = sum / fmaxf(cnt, 1.f);
    if (e <= s) mx = 0.f;
    __shared__ float agg[2*FF*AA];   // layout: agg[a*128 + t2], t2<64: mean, t2>=64: max
    agg[a*2*FF + f]      = mean;
    agg[a*2*FF + FF + f] = mx;
    __syncthreads();
    int d = t & 31, grp = t >> 5;    // 16 groups of 64 k-values
    float acc = 0.f;
    #pragma unroll
    for (int k2 = 0; k2 < 64; k2++) {
        int k = grp*64 + k2;
        acc += agg[k] * Wagg[k*DD + d];
    }
    __shared__ float red[16][DD];
    red[grp][d] = acc;
    __syncthreads();
    if (t < DD) {
        float r = 0.f;
        #pragma unroll
        for (int q = 0; q < 16; q++) r += red[q][t];
        aggW[g*DD + t] = r;
    }
}

// ---------------------------------------------------------------- out = tanh(h@W0 + xp@W1 + aggW[g] + b); accumulate global stats
__global__ __launch_bounds__(256) void k_out(const float* __restrict__ h,
                                             const float* __restrict__ xp,
                                             const float* __restrict__ aggW,
                                             const int* __restrict__ batch,
                                             const float* __restrict__ Wout,  // W_out[j], rows 0..95 used
                                             const float* __restrict__ bout,
                                             float* __restrict__ tbuf,
                                             float* __restrict__ stats) {
    int n = blockIdx.x * 256 + threadIdx.x;
    float s1 = 0.f, s2 = 0.f;
    if (n < NPTS) {
        int g = batch[n];
        float acc[DD];
        const float4* aw4 = (const float4*)(aggW + g*DD);
        #pragma unroll
        for (int i = 0; i < DD/4; i++) {
            float4 v = aw4[i];
            acc[4*i]   = v.x + bout[4*i];
            acc[4*i+1] = v.y + bout[4*i+1];
            acc[4*i+2] = v.z + bout[4*i+2];
            acc[4*i+3] = v.w + bout[4*i+3];
        }
        const float4* h4 = (const float4*)(h + (size_t)n*DD);
        #pragma unroll
        for (int i = 0; i < DD; i += 4) {
            float4 hv = h4[i/4];
            float hx[4] = {hv.x, hv.y, hv.z, hv.w};
            #pragma unroll
            for (int q = 0; q < 4; q++) {
                #pragma unroll
                for (int d = 0; d < DD; d++) acc[d] += hx[q] * Wout[(i+q)*DD + d];
            }
        }
        const float4* x4 = (const float4*)(xp + (size_t)n*FF);
        #pragma unroll
        for (int i = 0; i < FF; i += 4) {
            float4 xv = x4[i/4];
            float xx[4] = {xv.x, xv.y, xv.z, xv.w};
            #pragma unroll
            for (int q = 0; q < 4; q++) {
                #pragma unroll
                for (int d = 0; d < DD; d++) acc[d] += xx[q] * Wout[(DD+i+q)*DD + d];
            }
        }
        float4* to4 = (float4*)(tbuf + (size_t)n*DD);
        #pragma unroll
        for (int i = 0; i < DD; i += 4) {
            float4 o;
            o.x = tanhf(acc[i]);   o.y = tanhf(acc[i+1]);
            o.z = tanhf(acc[i+2]); o.w = tanhf(acc[i+3]);
            to4[i/4] = o;
            s1 += o.x + o.y + o.z + o.w;
            s2 += o.x*o.x + o.y*o.y + o.z*o.z + o.w*o.w;
        }
    }
    // block reduce -> atomic stats
    #pragma unroll
    for (int o = 32; o > 0; o >>= 1) { s1 += __shfl_down(s1, o); s2 += __shfl_down(s2, o); }
    __shared__ float rs1[4], rs2[4];
    int wid = threadIdx.x >> 6;
    if ((threadIdx.x & 63) == 0) { rs1[wid] = s1; rs2[wid] = s2; }
    __syncthreads();
    if (threadIdx.x == 0) {
        atomicAdd(&stats[0], rs1[0]+rs1[1]+rs1[2]+rs1[3]);
        atomicAdd(&stats[1], rs2[0]+rs2[1]+rs2[2]+rs2[3]);
    }
}

// ---------------------------------------------------------------- graph_ln apply: h = (t-m)/(std+eps)*w + b
__global__ __launch_bounds__(256) void k_gln(const float* __restrict__ tbuf,
                                             const float* __restrict__ stats,
                                             const float* __restrict__ gw,
                                             const float* __restrict__ gb,
                                             float* __restrict__ h) {
    int idx = (blockIdx.x * 256 + threadIdx.x) * 4;
    if (idx >= NPTS*DD) return;
    const float invM = 1.f / (float)(NPTS*DD);
    float m   = stats[0] * invM;
    float var = stats[1] * invM - m*m;
    float inv = 1.f / (sqrtf(fmaxf(var, 0.f)) + EPSV);
    float4 v = *(const float4*)(tbuf + idx);
    int d = idx & (DD-1);
    float4 w4 = *(const float4*)(gw + d);
    float4 b4 = *(const float4*)(gb + d);
    float4 r;
    r.x = (v.x - m)*inv*w4.x + b4.x;
    r.y = (v.y - m)*inv*w4.y + b4.y;
    r.z = (v.z - m)*inv*w4.z + b4.z;
    r.w = (v.w - m)*inv*w4.w + b4.w;
    *(float4*)(h + idx) = r;
}

// ---------------------------------------------------------------- readout: segment mean -> 3x (dense+ln+tanh) -> dot
__global__ __launch_bounds__(256) void k_read(const float* __restrict__ h,
                                              const int* __restrict__ offs,
                                              const float* __restrict__ Wp,
                                              const float* __restrict__ bp,
                                              const float* __restrict__ lnw,
                                              const float* __restrict__ lnb,
                                              const float* __restrict__ Wpo,
                                              const float* __restrict__ bpo,
                                              float* __restrict__ out) {
    int g = blockIdx.x;
    int t = threadIdx.x;
    int d = t & 31, pl = t >> 5;   // 8 point-lanes x 32 dims
    int s0 = offs[g], e0 = offs[g+1];
    float acc = 0.f;
    for (int n = s0 + pl; n < e0; n += 8) acc += h[(size_t)n*DD + d];
    __shared__ float red[8][DD];
    red[pl][d] = acc;
    __syncthreads();
    __shared__ float sv[DD];
    if (t < DD) {
        float r = 0.f;
        #pragma unroll
        for (int q = 0; q < 8; q++) r += red[q][t];
        float cnt = (float)(e0 - s0);
        sv[t] = r / fmaxf(cnt, 1.f);
    }
    __syncthreads();
    for (int j = 0; j < 3; j++) {
        float yv = 0.f;
        if (t < DD) {
            float y = bp[j*DD + t];
            #pragma unroll
            for (int i = 0; i < DD; i++) y += sv[i] * Wp[j*DD*DD + i*DD + t];
            // row LN across the 32 lanes (two-pass for accuracy)
            float sum = y;
            #pragma unroll
            for (int o = 1; o < 32; o <<= 1) sum += __shfl_xor(sum, o);
            float m = sum * (1.f/DD);
            float c = y - m;
            float sq = c*c;
            #pragma unroll
            for (int o = 1; o < 32; o <<= 1) sq += __shfl_xor(sq, o);
            float var = sq * (1.f/DD);
            yv = tanhf(c / sqrtf(var + EPSV) * lnw[j*DD + t] + lnb[j*DD + t]);
        }
        __syncthreads();
        if (t < DD) sv[t] = yv;
        __syncthreads();
    }
    if (t < DD) {
        float p = sv[t] * Wpo[t];
        #pragma unroll
        for (int o = 1; o < 32; o <<= 1) p += __shfl_xor(p, o);
        if (t == 0) out[g] = p + bpo[0];
    }
}

extern "C" void kernel_launch(void* const* d_in, const int* in_sizes, int n_in,
                              void* d_out, int out_size, void* d_ws, size_t ws_size,
                              hipStream_t stream) {
    const float* x     = (const float*)d_in[0];
    const int*   batch = (const int*)  d_in[1];
    const float* Wi    = (const float*)d_in[2];
    const float* bi    = (const float*)d_in[3];
    const float* lni_w = (const float*)d_in[4];
    const float* lni_b = (const float*)d_in[5];
    const float* W_in  = (const float*)d_in[6];
    const float* b_in  = (const float*)d_in[7];
    const float* W_sc  = (const float*)d_in[8];
    const float* b_sc  = (const float*)d_in[9];
    const float* W_out = (const float*)d_in[10];
    const float* b_out = (const float*)d_in[11];
    const float* gln_w = (const float*)d_in[12];
    const float* gln_b = (const float*)d_in[13];
    const float* Wp    = (const float*)d_in[14];
    const float* bp    = (const float*)d_in[15];
    const float* lnp_w = (const float*)d_in[16];
    const float* lnp_b = (const float*)d_in[17];
    const float* Wpo   = (const float*)d_in[18];
    const float* bpo   = (const float*)d_in[19];
    float* out = (float*)d_out;

    float* ws    = (float*)d_ws;
    float* h     = ws;                          // NPTS*32
    float* xp    = h    + (size_t)NPTS*DD;      // NPTS*64
    float* attn  = xp   + (size_t)NPTS*FF;      // NPTS*8
    float* tbuf  = attn + (size_t)NPTS*AA;      // NPTS*32
    float* aggW  = tbuf + (size_t)NPTS*DD;      // NG*32
    float* stats = aggW + (size_t)NG*DD;        // 32 (18 used: 2 per layer-invocation)
    int*   offs  = (int*)(stats + 32);          // NG+1

    k_init<<<1, 256, 0, stream>>>(batch, offs, stats);
    k_embed<<<(NPTS+255)/256, 256, 0, stream>>>(x, Wi, bi, lni_w, lni_b, h);

    for (int it = 0; it < 3; it++) {
        for (int j = 0; j < 3; j++) {
            int L = it*3 + j;
            k_xp<<<(NPTS+255)/256, 256, 0, stream>>>(
                h, W_in + (size_t)j*DD*FF, b_in + j*FF, W_sc + (size_t)j*FF*AA, b_sc + j*AA, xp, attn);
            k_agg<<<NG, 512, 0, stream>>>(
                xp, attn, offs, W_out + (size_t)j*HINC*DD + (size_t)96*DD, aggW);
            k_out<<<(NPTS+255)/256, 256, 0, stream>>>(
                h, xp, aggW, batch, W_out + (size_t)j*HINC*DD, b_out + j*DD, tbuf, stats + 2*L);
            k_gln<<<(NPTS*DD/4 + 255)/256, 256, 0, stream>>>(
                tbuf, stats + 2*L, gln_w + j*DD, gln_b + j*DD, h);
        }
    }
    k_read<<<NG, 256, 0, stream>>>(h, offs, Wp, bp, lnp_w, lnp_b, Wpo, bpo, out);
}

// Round 2
// 730.002 us; speedup vs baseline: 9.6930x; 9.6930x over previous
//
#include <hip/hip_runtime.h>
#include <math.h>

#define NPTS 50000
#define NG   128
#define DD   32
#define FF   64
#define AA   8
#define HINC 1120   // DD + FF + 2*FF*AA
#define EPSV 1e-5f
#define NBLK 196    // (NPTS+255)/256

__device__ __forceinline__ float tanh_fast(float x) {
    float e = __expf(-2.f * fabsf(x));
    float r = __fdividef(1.f - e, 1.f + e);
    return copysignf(r, x);
}

// ---------------------------------------------------------------- init: segment offsets + zero stats
__global__ __launch_bounds__(256) void k_init(const int* __restrict__ batch,
                                              int* __restrict__ offs,
                                              float* __restrict__ stats) {
    int t = threadIdx.x;
    if (t <= NG) {
        int lo = 0, hi = NPTS;
        while (lo < hi) { int mid = (lo + hi) >> 1; if (batch[mid] < t) lo = mid + 1; else hi = mid; }
        offs[t] = lo;
    }
    if (t < 32) stats[t] = 0.f;
}

// ---------------------------------------------------------------- fold: Weff = W0 + Win@W1, beff = bout + bin@W1
__global__ __launch_bounds__(256) void k_fold(const float* __restrict__ W_in,
                                              const float* __restrict__ b_in,
                                              const float* __restrict__ W_out,
                                              const float* __restrict__ b_out,
                                              float* __restrict__ Weff,
                                              float* __restrict__ beff) {
    int j = blockIdx.x, t = threadIdx.x;
    const float* W0 = W_out + (size_t)j * HINC * DD;    // rows 0..31
    const float* W1 = W0 + DD * DD;                      // rows 32..95
    const float* Wi = W_in + (size_t)j * DD * FF;
    for (int e = t; e < DD * DD; e += 256) {
        int i = e >> 5, d = e & 31;
        float s = W0[e];
        for (int f = 0; f < FF; f++) s += Wi[i * FF + f] * W1[f * DD + d];
        Weff[j * DD * DD + e] = s;
    }
    if (t < DD) {
        float s = b_out[j * DD + t];
        for (int f = 0; f < FF; f++) s += b_in[j * FF + f] * W1[f * DD + t];
        beff[j * DD + t] = s;
    }
}

// ---------------------------------------------------------------- embed: h = tanh(ln(x@Wi+bi))
__global__ __launch_bounds__(256) void k_embed(const float* __restrict__ x,
                                               const float* __restrict__ Wi,
                                               const float* __restrict__ bi,
                                               const float* __restrict__ lw,
                                               const float* __restrict__ lb,
                                               float* __restrict__ h) {
    int n = blockIdx.x * 256 + threadIdx.x;
    if (n >= NPTS) return;
    float x0 = x[n*3+0], x1 = x[n*3+1], x2 = x[n*3+2];
    float v[DD]; float m = 0.f;
    #pragma unroll
    for (int d = 0; d < DD; d++) {
        float t = x0*Wi[d] + x1*Wi[DD+d] + x2*Wi[2*DD+d] + bi[d];
        v[d] = t; m += t;
    }
    m *= (1.f/DD);
    float var = 0.f;
    #pragma unroll
    for (int d = 0; d < DD; d++) { float c = v[d]-m; var += c*c; }
    var *= (1.f/DD);
    float inv = 1.f/sqrtf(var + EPSV);
    #pragma unroll
    for (int d = 0; d < DD; d++) h[(size_t)n*DD + d] = tanh_fast((v[d]-m)*inv*lw[d] + lb[d]);
}

// ---------------------------------------------------------------- xp = gln(in)@Win+bin ; attn = exp(-|xp@Wsc+bsc|)
__global__ __launch_bounds__(256) void k_xp(const float* __restrict__ inb,
                                            const float* __restrict__ stats,
                                            const float* __restrict__ gw,
                                            const float* __restrict__ gb,
                                            const float* __restrict__ Win,
                                            const float* __restrict__ bin,
                                            const float* __restrict__ Wsc,
                                            const float* __restrict__ bsc,
                                            float* __restrict__ xp,
                                            float* __restrict__ attn) {
    __shared__ float sW[DD*FF];     // Win row-major
    __shared__ float sSt[AA*FF];    // Wsc transposed: [a][f]
    __shared__ float sb[FF];
    __shared__ float ss[AA];
    __shared__ float sg[DD], sgb[DD];
    int t = threadIdx.x;
    for (int k = t; k < DD*FF; k += 256) sW[k] = Win[k];
    for (int k = t; k < AA*FF; k += 256) { int a = k >> 6, f = k & 63; sSt[k] = Wsc[f*AA + a]; }
    if (t < FF) sb[t] = bin[t];
    if (t < AA) ss[t] = bsc[t];
    if (t < DD) { sg[t] = gw ? gw[t] : 1.f; sgb[t] = gb ? gb[t] : 0.f; }
    __syncthreads();
    int n = blockIdx.x * 256 + t;
    if (n >= NPTS) return;
    float m = 0.f, inv = 1.f;
    if (stats) {
        const float invM = 1.f / ((float)NPTS * DD);
        m = stats[0] * invM;
        float var = stats[1] * invM - m*m;
        inv = 1.f / (sqrtf(fmaxf(var, 0.f)) + EPSV);
    }
    float hr[DD];
    const float4* r4 = (const float4*)(inb + (size_t)n*DD);
    #pragma unroll
    for (int i = 0; i < DD/4; i++) {
        float4 v = r4[i];
        hr[4*i+0] = (v.x - m)*inv*sg[4*i+0] + sgb[4*i+0];
        hr[4*i+1] = (v.y - m)*inv*sg[4*i+1] + sgb[4*i+1];
        hr[4*i+2] = (v.z - m)*inv*sg[4*i+2] + sgb[4*i+2];
        hr[4*i+3] = (v.w - m)*inv*sg[4*i+3] + sgb[4*i+3];
    }
    float xr[FF];
    #pragma unroll
    for (int f = 0; f < FF/4; f++) {
        float4 b = *(const float4*)&sb[4*f];
        xr[4*f] = b.x; xr[4*f+1] = b.y; xr[4*f+2] = b.z; xr[4*f+3] = b.w;
    }
    #pragma unroll
    for (int i = 0; i < DD; i++) {
        float hv = hr[i];
        #pragma unroll
        for (int f4 = 0; f4 < FF/4; f4++) {
            float4 w = *(const float4*)&sW[i*FF + 4*f4];
            xr[4*f4]   += hv * w.x;
            xr[4*f4+1] += hv * w.y;
            xr[4*f4+2] += hv * w.z;
            xr[4*f4+3] += hv * w.w;
        }
    }
    float ar[AA];
    #pragma unroll
    for (int a = 0; a < AA; a++) {
        float acc = ss[a];
        #pragma unroll
        for (int f4 = 0; f4 < FF/4; f4++) {
            float4 w = *(const float4*)&sSt[a*FF + 4*f4];
            acc += xr[4*f4]*w.x + xr[4*f4+1]*w.y + xr[4*f4+2]*w.z + xr[4*f4+3]*w.w;
        }
        ar[a] = __expf(-fabsf(acc));
    }
    float4* xo = (float4*)(xp + (size_t)n*FF);
    #pragma unroll
    for (int i = 0; i < FF/4; i++) {
        float4 v; v.x = xr[4*i]; v.y = xr[4*i+1]; v.z = xr[4*i+2]; v.w = xr[4*i+3];
        xo[i] = v;
    }
    float4* ao = (float4*)(attn + (size_t)n*AA);
    float4 a0; a0.x = ar[0]; a0.y = ar[1]; a0.z = ar[2]; a0.w = ar[3];
    float4 a1; a1.x = ar[4]; a1.y = ar[5]; a1.z = ar[6]; a1.w = ar[7];
    ao[0] = a0; ao[1] = a1;
}

// ---------------------------------------------------------------- per-graph agg (mean+max of attn*xp) then aggW = agg @ Wagg + beff
__global__ __launch_bounds__(512) void k_agg(const float* __restrict__ xp,
                                             const float* __restrict__ attn,
                                             const int* __restrict__ offs,
                                             const float* __restrict__ Wagg,  // W_out[j] + 96*DD
                                             const float* __restrict__ beff,
                                             float* __restrict__ aggW) {
    int g = blockIdx.x;
    int t = threadIdx.x;           // 512 = AA * FF
    int a = t >> 6, f = t & 63;
    int s = offs[g], e = offs[g+1];
    float sum = 0.f, mx = -INFINITY;
    int nn = s;
    for (; nn + 3 < e; nn += 4) {
        float w0 = attn[(size_t)(nn+0)*AA + a] * xp[(size_t)(nn+0)*FF + f];
        float w1 = attn[(size_t)(nn+1)*AA + a] * xp[(size_t)(nn+1)*FF + f];
        float w2 = attn[(size_t)(nn+2)*AA + a] * xp[(size_t)(nn+2)*FF + f];
        float w3 = attn[(size_t)(nn+3)*AA + a] * xp[(size_t)(nn+3)*FF + f];
        sum += (w0 + w1) + (w2 + w3);
        mx = fmaxf(mx, fmaxf(fmaxf(w0, w1), fmaxf(w2, w3)));
    }
    for (; nn < e; nn++) {
        float w = attn[(size_t)nn*AA + a] * xp[(size_t)nn*FF + f];
        sum += w; mx = fmaxf(mx, w);
    }
    float cnt = (float)(e - s);
    float mean = sum / fmaxf(cnt, 1.f);
    if (e <= s) mx = 0.f;
    __shared__ float agg[2*FF*AA];
    agg[a*2*FF + f]      = mean;
    agg[a*2*FF + FF + f] = mx;
    __syncthreads();
    int d = t & 31, grp = t >> 5;    // 16 groups of 64 k-values
    float acc = 0.f;
    #pragma unroll
    for (int k2 = 0; k2 < 64; k2++) {
        int k = grp*64 + k2;
        acc += agg[k] * Wagg[k*DD + d];
    }
    __shared__ float red[16][DD];
    red[grp][d] = acc;
    __syncthreads();
    if (t < DD) {
        float r = 0.f;
        #pragma unroll
        for (int q = 0; q < 16; q++) r += red[q][t];
        aggW[g*DD + t] = r + beff[t];
    }
}

// ---------------------------------------------------------------- out = tanh(gln(in)@Weff + aggW[g]); accumulate global stats
__global__ __launch_bounds__(256) void k_out(const float* __restrict__ inb,
                                             const float* __restrict__ stats,
                                             const float* __restrict__ gw,
                                             const float* __restrict__ gb,
                                             const float* __restrict__ aggW,
                                             const int* __restrict__ batch,
                                             const float* __restrict__ Weff,
                                             float* __restrict__ tbuf,
                                             float* __restrict__ statsO) {
    __shared__ float sW[DD*DD];
    __shared__ float sg[DD], sgb[DD];
    int t = threadIdx.x;
    for (int k = t; k < DD*DD; k += 256) sW[k] = Weff[k];
    if (t < DD) { sg[t] = gw ? gw[t] : 1.f; sgb[t] = gb ? gb[t] : 0.f; }
    __syncthreads();
    int n = blockIdx.x * 256 + t;
    float s1 = 0.f, s2 = 0.f;
    if (n < NPTS) {
        float m = 0.f, inv = 1.f;
        if (stats) {
            const float invM = 1.f / ((float)NPTS * DD);
            m = stats[0] * invM;
            float var = stats[1] * invM - m*m;
            inv = 1.f / (sqrtf(fmaxf(var, 0.f)) + EPSV);
        }
        float hr[DD];
        const float4* r4 = (const float4*)(inb + (size_t)n*DD);
        #pragma unroll
        for (int i = 0; i < DD/4; i++) {
            float4 v = r4[i];
            hr[4*i+0] = (v.x - m)*inv*sg[4*i+0] + sgb[4*i+0];
            hr[4*i+1] = (v.y - m)*inv*sg[4*i+1] + sgb[4*i+1];
            hr[4*i+2] = (v.z - m)*inv*sg[4*i+2] + sgb[4*i+2];
            hr[4*i+3] = (v.w - m)*inv*sg[4*i+3] + sgb[4*i+3];
        }
        int g = batch[n];
        float acc[DD];
        const float4* aw4 = (const float4*)(aggW + g*DD);
        #pragma unroll
        for (int i = 0; i < DD/4; i++) {
            float4 v = aw4[i];
            acc[4*i] = v.x; acc[4*i+1] = v.y; acc[4*i+2] = v.z; acc[4*i+3] = v.w;
        }
        #pragma unroll
        for (int i = 0; i < DD; i++) {
            float hv = hr[i];
            #pragma unroll
            for (int d4 = 0; d4 < DD/4; d4++) {
                float4 w = *(const float4*)&sW[i*DD + 4*d4];
                acc[4*d4]   += hv * w.x;
                acc[4*d4+1] += hv * w.y;
                acc[4*d4+2] += hv * w.z;
                acc[4*d4+3] += hv * w.w;
            }
        }
        float4* to4 = (float4*)(tbuf + (size_t)n*DD);
        #pragma unroll
        for (int i = 0; i < DD; i += 4) {
            float4 o;
            o.x = tanh_fast(acc[i]);   o.y = tanh_fast(acc[i+1]);
            o.z = tanh_fast(acc[i+2]); o.w = tanh_fast(acc[i+3]);
            to4[i/4] = o;
            s1 += (o.x + o.y) + (o.z + o.w);
            s2 += (o.x*o.x + o.y*o.y) + (o.z*o.z + o.w*o.w);
        }
    }
    #pragma unroll
    for (int o = 32; o > 0; o >>= 1) { s1 += __shfl_down(s1, o); s2 += __shfl_down(s2, o); }
    __shared__ float rs1[4], rs2[4];
    int wid = threadIdx.x >> 6;
    if ((threadIdx.x & 63) == 0) { rs1[wid] = s1; rs2[wid] = s2; }
    __syncthreads();
    if (threadIdx.x == 0) {
        atomicAdd(&statsO[0], rs1[0]+rs1[1]+rs1[2]+rs1[3]);
        atomicAdd(&statsO[1], rs2[0]+rs2[1]+rs2[2]+rs2[3]);
    }
}

// ---------------------------------------------------------------- readout: segment mean of gln(tbuf) -> 3x (dense+ln+tanh) -> dot
__global__ __launch_bounds__(256) void k_read(const float* __restrict__ tbuf,
                                              const float* __restrict__ stats,
                                              const float* __restrict__ gw,
                                              const float* __restrict__ gb,
                                              const int* __restrict__ offs,
                                              const float* __restrict__ Wp,
                                              const float* __restrict__ bp,
                                              const float* __restrict__ lnw,
                                              const float* __restrict__ lnb,
                                              const float* __restrict__ Wpo,
                                              const float* __restrict__ bpo,
                                              float* __restrict__ out) {
    int g = blockIdx.x;
    int t = threadIdx.x;
    int d = t & 31, pl = t >> 5;   // 8 point-lanes x 32 dims
    int s0 = offs[g], e0 = offs[g+1];
    float acc = 0.f;
    for (int n = s0 + pl; n < e0; n += 8) acc += tbuf[(size_t)n*DD + d];
    __shared__ float red[8][DD];
    red[pl][d] = acc;
    __syncthreads();
    __shared__ float sv[DD];
    if (t < DD) {
        float r = 0.f;
        #pragma unroll
        for (int q = 0; q < 8; q++) r += red[q][t];
        const float invM = 1.f / ((float)NPTS * DD);
        float m = stats[0] * invM;
        float var = stats[1] * invM - m*m;
        float inv = 1.f / (sqrtf(fmaxf(var, 0.f)) + EPSV);
        float cnt = (float)(e0 - s0);
        float mean = r / fmaxf(cnt, 1.f);
        sv[t] = (e0 > s0) ? (mean - m)*inv*gw[t] + gb[t] : 0.f;
    }
    __syncthreads();
    for (int j = 0; j < 3; j++) {
        float yv = 0.f;
        if (t < DD) {
            float y = bp[j*DD + t];
            #pragma unroll
            for (int i = 0; i < DD; i++) y += sv[i] * Wp[j*DD*DD + i*DD + t];
            float sum = y;
            #pragma unroll
            for (int o = 1; o < 32; o <<= 1) sum += __shfl_xor(sum, o);
            float m = sum * (1.f/DD);
            float c = y - m;
            float sq = c*c;
            #pragma unroll
            for (int o = 1; o < 32; o <<= 1) sq += __shfl_xor(sq, o);
            float var = sq * (1.f/DD);
            yv = tanh_fast(c / sqrtf(var + EPSV) * lnw[j*DD + t] + lnb[j*DD + t]);
        }
        __syncthreads();
        if (t < DD) sv[t] = yv;
        __syncthreads();
    }
    if (t < DD) {
        float p = sv[t] * Wpo[t];
        #pragma unroll
        for (int o = 1; o < 32; o <<= 1) p += __shfl_xor(p, o);
        if (t == 0) out[g] = p + bpo[0];
    }
}

extern "C" void kernel_launch(void* const* d_in, const int* in_sizes, int n_in,
                              void* d_out, int out_size, void* d_ws, size_t ws_size,
                              hipStream_t stream) {
    const float* x     = (const float*)d_in[0];
    const int*   batch = (const int*)  d_in[1];
    const float* Wi    = (const float*)d_in[2];
    const float* bi    = (const float*)d_in[3];
    const float* lni_w = (const float*)d_in[4];
    const float* lni_b = (const float*)d_in[5];
    const float* W_in  = (const float*)d_in[6];
    const float* b_in  = (const float*)d_in[7];
    const float* W_sc  = (const float*)d_in[8];
    const float* b_sc  = (const float*)d_in[9];
    const float* W_out = (const float*)d_in[10];
    const float* b_out = (const float*)d_in[11];
    const float* gln_w = (const float*)d_in[12];
    const float* gln_b = (const float*)d_in[13];
    const float* Wp    = (const float*)d_in[14];
    const float* bp    = (const float*)d_in[15];
    const float* lnp_w = (const float*)d_in[16];
    const float* lnp_b = (const float*)d_in[17];
    const float* Wpo   = (const float*)d_in[18];
    const float* bpo   = (const float*)d_in[19];
    float* out = (float*)d_out;

    float* ws    = (float*)d_ws;
    float* h     = ws;                          // NPTS*32
    float* xp    = h    + (size_t)NPTS*DD;      // NPTS*64
    float* attn  = xp   + (size_t)NPTS*FF;      // NPTS*8
    float* tbuf  = attn + (size_t)NPTS*AA;      // NPTS*32
    float* aggW  = tbuf + (size_t)NPTS*DD;      // NG*32
    float* stats = aggW + (size_t)NG*DD;        // 32
    float* Weff  = stats + 32;                  // 3*32*32
    float* beff  = Weff + 3*DD*DD;              // 3*32
    int*   offs  = (int*)(beff + 3*DD);         // NG+1

    k_init<<<1, 256, 0, stream>>>(batch, offs, stats);
    k_fold<<<3, 256, 0, stream>>>(W_in, b_in, W_out, b_out, Weff, beff);
    k_embed<<<NBLK, 256, 0, stream>>>(x, Wi, bi, lni_w, lni_b, h);

    for (int it = 0; it < 3; it++) {
        for (int j = 0; j < 3; j++) {
            int L = it*3 + j;
            const float* inb = L ? tbuf : h;
            const float* st  = L ? stats + 2*(L-1) : nullptr;
            int pj = (L + 2) % 3;  // (L-1)%3 for L>=1
            const float* pgw = L ? gln_w + pj*DD : nullptr;
            const float* pgb = L ? gln_b + pj*DD : nullptr;
            k_xp<<<NBLK, 256, 0, stream>>>(
                inb, st, pgw, pgb,
                W_in + (size_t)j*DD*FF, b_in + j*FF, W_sc + (size_t)j*FF*AA, b_sc + j*AA,
                xp, attn);
            k_agg<<<NG, 512, 0, stream>>>(
                xp, attn, offs, W_out + (size_t)j*HINC*DD + (size_t)96*DD, beff + j*DD, aggW);
            k_out<<<NBLK, 256, 0, stream>>>(
                inb, st, pgw, pgb, aggW, batch, Weff + (size_t)j*DD*DD, tbuf, stats + 2*L);
        }
    }
    k_read<<<NG, 256, 0, stream>>>(tbuf, stats + 16, gln_w + 2*DD, gln_b + 2*DD,
                                   offs, Wp, bp, lnp_w, lnp_b, Wpo, bpo, out);
}

// Round 3
// 465.071 us; speedup vs baseline: 15.2147x; 1.5697x over previous
//
#include <hip/hip_runtime.h>
#include <math.h>

#define NPTS 50000
#define NG   128
#define DD   32
#define FF   64
#define AA   8
#define HINC 1120   // DD + FF + 2*FF*AA
#define EPSV 1e-5f
#define CH   64     // points per chunk
#define SMAX 10     // chunk slots per graph (last slot loops for overflow)

__device__ __forceinline__ float tanh_fast(float x) {
    float e = __expf(-2.f * fabsf(x));
    float r = __fdividef(1.f - e, 1.f + e);
    return copysignf(r, x);
}

// ---------------------------------------------------------------- init: segment offsets + zero stats
__global__ __launch_bounds__(256) void k_init(const int* __restrict__ batch,
                                              int* __restrict__ offs,
                                              float* __restrict__ stats) {
    int t = threadIdx.x;
    if (t <= NG) {
        int lo = 0, hi = NPTS;
        while (lo < hi) { int mid = (lo + hi) >> 1; if (batch[mid] < t) lo = mid + 1; else hi = mid; }
        offs[t] = lo;
    }
    if (t < 32) stats[t] = 0.f;
}

// ---------------------------------------------------------------- fold: Weff = W0 + Win@W1, beff = bout + bin@W1
__global__ __launch_bounds__(256) void k_fold(const float* __restrict__ W_in,
                                              const float* __restrict__ b_in,
                                              const float* __restrict__ W_out,
                                              const float* __restrict__ b_out,
                                              float* __restrict__ Weff,
                                              float* __restrict__ beff) {
    int j = blockIdx.x, t = threadIdx.x;
    const float* W0 = W_out + (size_t)j * HINC * DD;    // rows 0..31
    const float* W1 = W0 + DD * DD;                      // rows 32..95
    const float* Wi = W_in + (size_t)j * DD * FF;
    for (int e = t; e < DD * DD; e += 256) {
        int i = e >> 5, d = e & 31;
        float s = W0[e];
        for (int f = 0; f < FF; f++) s += Wi[i * FF + f] * W1[f * DD + d];
        Weff[j * DD * DD + e] = s;
    }
    if (t < DD) {
        float s = b_out[j * DD + t];
        for (int f = 0; f < FF; f++) s += b_in[j * FF + f] * W1[f * DD + t];
        beff[j * DD + t] = s;
    }
}

// ---------------------------------------------------------------- embed: h = tanh(ln(x@Wi+bi))
__global__ __launch_bounds__(256) void k_embed(const float* __restrict__ x,
                                               const float* __restrict__ Wi,
                                               const float* __restrict__ bi,
                                               const float* __restrict__ lw,
                                               const float* __restrict__ lb,
                                               float* __restrict__ h) {
    int n = blockIdx.x * 256 + threadIdx.x;
    if (n >= NPTS) return;
    float x0 = x[n*3+0], x1 = x[n*3+1], x2 = x[n*3+2];
    float v[DD]; float m = 0.f;
    #pragma unroll
    for (int d = 0; d < DD; d++) {
        float t = x0*Wi[d] + x1*Wi[DD+d] + x2*Wi[2*DD+d] + bi[d];
        v[d] = t; m += t;
    }
    m *= (1.f/DD);
    float var = 0.f;
    #pragma unroll
    for (int d = 0; d < DD; d++) { float c = v[d]-m; var += c*c; }
    var *= (1.f/DD);
    float inv = 1.f/sqrtf(var + EPSV);
    #pragma unroll
    for (int d = 0; d < DD; d++) h[(size_t)n*DD + d] = tanh_fast((v[d]-m)*inv*lw[d] + lb[d]);
}

// ---------------------------------------------------------------- kA: per-graph-chunk gln -> xp -> attn -> partial agg (LDS only)
__global__ __launch_bounds__(512) void k_A(const float* __restrict__ inb,
                                           const float* __restrict__ stats,
                                           const float* __restrict__ gw,
                                           const float* __restrict__ gb,
                                           const float* __restrict__ Win,
                                           const float* __restrict__ bin,
                                           const float* __restrict__ Wsc,
                                           const float* __restrict__ bsc,
                                           const int* __restrict__ offs,
                                           float* __restrict__ psum,
                                           float* __restrict__ pmax) {
    int g = blockIdx.x / SMAX;
    int s = blockIdx.x - g * SMAX;
    int gs = offs[g], ge = offs[g+1];
    int cnt = ge - gs;
    int start = s * CH;
    if (start >= cnt) return;                       // uniform early exit, no syncs yet
    int end = (s == SMAX-1) ? cnt : min(cnt, start + CH);

    __shared__ float hs[CH][36];        // gln'd input rows
    __shared__ float sxp[CH][68];       // xp rows
    __shared__ float sattn[CH][9];      // attn rows
    __shared__ float sWin[DD*FF];
    __shared__ float sScT[AA*FF];       // Wsc transposed [a][f]

    int t = threadIdx.x;
    for (int k = t; k < DD*FF; k += 512) sWin[k] = Win[k];
    if (t < AA*FF) { int a = t >> 6, f = t & 63; sScT[t] = Wsc[f*AA + a]; }

    float m = 0.f, inv = 1.f;
    if (stats) {
        const float invM = 1.f / ((float)NPTS * DD);
        m = stats[0] * invM;
        float var = stats[1] * invM - m*m;
        inv = 1.f / (sqrtf(fmaxf(var, 0.f)) + EPSV);
    }

    // phase-2 ids: one point per thread, 8 f-outputs
    int pt = t >> 3, fo = (t & 7) * 8;
    float bscv = bsc[t & 7];
    float4 bi0 = *(const float4*)&bin[fo];
    float4 bi1 = *(const float4*)&bin[fo + 4];
    // phase-3 cell: c = t  (a = t>>6, f = t&63)
    int ca = t >> 6, cf = t & 63;
    float csum = 0.f, cmax = -INFINITY;

    for (int base = start; base < end; base += CH) {
        int np = min(CH, end - base);
        __syncthreads();                       // protect LDS from prev iter readers
        // ---- phase 1: load + gln (1 float4 per thread)
        {
            int p = t >> 3, d4 = (t & 7) * 4;
            if (p < np) {
                int n = gs + base + p;
                float4 v = *(const float4*)&inb[(size_t)n*DD + d4];
                float4 w4, b4;
                if (gw) { w4 = *(const float4*)&gw[d4]; b4 = *(const float4*)&gb[d4]; }
                else { w4 = make_float4(1.f,1.f,1.f,1.f); b4 = make_float4(0.f,0.f,0.f,0.f); }
                hs[p][d4+0] = (v.x - m)*inv*w4.x + b4.x;
                hs[p][d4+1] = (v.y - m)*inv*w4.y + b4.y;
                hs[p][d4+2] = (v.z - m)*inv*w4.z + b4.z;
                hs[p][d4+3] = (v.w - m)*inv*w4.w + b4.w;
            }
        }
        __syncthreads();
        // ---- phase 2: xp + attn
        if (pt < np) {
            float xr[8];
            xr[0]=bi0.x; xr[1]=bi0.y; xr[2]=bi0.z; xr[3]=bi0.w;
            xr[4]=bi1.x; xr[5]=bi1.y; xr[6]=bi1.z; xr[7]=bi1.w;
            #pragma unroll
            for (int k = 0; k < DD; k++) {
                float hv = hs[pt][k];
                float4 wa = *(const float4*)&sWin[k*FF + fo];
                float4 wb = *(const float4*)&sWin[k*FF + fo + 4];
                xr[0] += hv*wa.x; xr[1] += hv*wa.y; xr[2] += hv*wa.z; xr[3] += hv*wa.w;
                xr[4] += hv*wb.x; xr[5] += hv*wb.y; xr[6] += hv*wb.z; xr[7] += hv*wb.w;
            }
            float pa[8];
            #pragma unroll
            for (int a = 0; a < 8; a++) {
                float4 wa = *(const float4*)&sScT[a*FF + fo];
                float4 wb = *(const float4*)&sScT[a*FF + fo + 4];
                pa[a] = xr[0]*wa.x + xr[1]*wa.y + xr[2]*wa.z + xr[3]*wa.w
                      + xr[4]*wb.x + xr[5]*wb.y + xr[6]*wb.z + xr[7]*wb.w;
            }
            #pragma unroll
            for (int msk = 1; msk < 8; msk <<= 1) {
                #pragma unroll
                for (int a = 0; a < 8; a++) pa[a] += __shfl_xor(pa[a], msk);
            }
            int al = t & 7;
            sattn[pt][al] = __expf(-fabsf(pa[al] + bscv));
            *(float4*)&sxp[pt][fo]     = make_float4(xr[0], xr[1], xr[2], xr[3]);
            *(float4*)&sxp[pt][fo + 4] = make_float4(xr[4], xr[5], xr[6], xr[7]);
        }
        __syncthreads();
        // ---- phase 3: accumulate one (a,f) cell over np points
        for (int p = 0; p < np; p++) {
            float w = sattn[p][ca] * sxp[p][cf];
            csum += w;
            cmax = fmaxf(cmax, w);
        }
    }
    size_t pb = ((size_t)g * SMAX + s) * 512;
    psum[pb + t] = csum;
    pmax[pb + t] = cmax;
}

// ---------------------------------------------------------------- kB: reduce partials -> agg -> aggW = agg@Wagg + beff
__global__ __launch_bounds__(512) void k_B(const float* __restrict__ psum,
                                           const float* __restrict__ pmax,
                                           const int* __restrict__ offs,
                                           const float* __restrict__ Wagg,  // W_out[j] + 96*DD
                                           const float* __restrict__ beff,
                                           float* __restrict__ aggW) {
    int g = blockIdx.x, t = threadIdx.x;
    int cnt = offs[g+1] - offs[g];
    int nch = min((cnt + CH - 1) / CH, SMAX);
    float sum = 0.f, mx = -INFINITY;
    size_t pb = (size_t)g * SMAX * 512;
    for (int s = 0; s < nch; s++) {
        sum += psum[pb + s*512 + t];
        mx = fmaxf(mx, pmax[pb + s*512 + t]);
    }
    float mean = sum / fmaxf((float)cnt, 1.f);
    if (cnt <= 0) { mean = 0.f; mx = 0.f; }
    __shared__ float agg[2*FF*AA];
    int a = t >> 6, f = t & 63;
    agg[a*2*FF + f]      = mean;
    agg[a*2*FF + FF + f] = mx;
    __syncthreads();
    int d = t & 31, grp = t >> 5;    // 16 groups x 64 k
    float acc = 0.f;
    #pragma unroll
    for (int k2 = 0; k2 < 64; k2++) {
        int k = grp*64 + k2;
        acc += agg[k] * Wagg[k*DD + d];
    }
    __shared__ float red[16][DD];
    red[grp][d] = acc;
    __syncthreads();
    if (t < DD) {
        float r = 0.f;
        #pragma unroll
        for (int q = 0; q < 16; q++) r += red[q][t];
        aggW[g*DD + t] = r + beff[t];
    }
}

// ---------------------------------------------------------------- kC: out = tanh(gln(in)@Weff + aggW[g]); global stats
__global__ __launch_bounds__(512) void k_C(const float* inb,
                                           const float* __restrict__ stats,
                                           const float* __restrict__ gw,
                                           const float* __restrict__ gb,
                                           const float* __restrict__ aggW,
                                           const int* __restrict__ batch,
                                           const float* __restrict__ Weff,
                                           float* tbuf,
                                           float* __restrict__ statsO) {
    __shared__ float hs[64][36];
    __shared__ float sW[DD][36];
    int t = threadIdx.x;
    for (int k = t; k < DD*DD; k += 512) sW[k >> 5][k & 31] = Weff[k];

    float m = 0.f, inv = 1.f;
    if (stats) {
        const float invM = 1.f / ((float)NPTS * DD);
        m = stats[0] * invM;
        float var = stats[1] * invM - m*m;
        inv = 1.f / (sqrtf(fmaxf(var, 0.f)) + EPSV);
    }
    int b0 = blockIdx.x * 64;
    // phase 1: load + gln
    {
        int p = t >> 3, d4 = (t & 7) * 4;
        int n = b0 + p;
        if (n < NPTS) {
            float4 v = *(const float4*)&inb[(size_t)n*DD + d4];
            float4 w4, b4;
            if (gw) { w4 = *(const float4*)&gw[d4]; b4 = *(const float4*)&gb[d4]; }
            else { w4 = make_float4(1.f,1.f,1.f,1.f); b4 = make_float4(0.f,0.f,0.f,0.f); }
            hs[p][d4+0] = (v.x - m)*inv*w4.x + b4.x;
            hs[p][d4+1] = (v.y - m)*inv*w4.y + b4.y;
            hs[p][d4+2] = (v.z - m)*inv*w4.z + b4.z;
            hs[p][d4+3] = (v.w - m)*inv*w4.w + b4.w;
        }
    }
    __syncthreads();
    int pt = t >> 3, q4 = (t & 7) * 4;
    int n = b0 + pt;
    float s1 = 0.f, s2 = 0.f;
    if (n < NPTS) {
        int g = batch[n];
        float4 a0 = *(const float4*)&aggW[g*DD + q4];
        float acc[4] = {a0.x, a0.y, a0.z, a0.w};
        #pragma unroll
        for (int k = 0; k < DD; k++) {
            float hv = hs[pt][k];
            float4 w = *(const float4*)&sW[k][q4];
            acc[0] += hv*w.x; acc[1] += hv*w.y; acc[2] += hv*w.z; acc[3] += hv*w.w;
        }
        float4 o;
        o.x = tanh_fast(acc[0]); o.y = tanh_fast(acc[1]);
        o.z = tanh_fast(acc[2]); o.w = tanh_fast(acc[3]);
        *(float4*)&tbuf[(size_t)n*DD + q4] = o;
        s1 = (o.x + o.y) + (o.z + o.w);
        s2 = (o.x*o.x + o.y*o.y) + (o.z*o.z + o.w*o.w);
    }
    #pragma unroll
    for (int o = 32; o > 0; o >>= 1) { s1 += __shfl_down(s1, o); s2 += __shfl_down(s2, o); }
    __shared__ float rs1[8], rs2[8];
    int wid = t >> 6;
    if ((t & 63) == 0) { rs1[wid] = s1; rs2[wid] = s2; }
    __syncthreads();
    if (t == 0) {
        float a1 = 0.f, a2 = 0.f;
        #pragma unroll
        for (int q = 0; q < 8; q++) { a1 += rs1[q]; a2 += rs2[q]; }
        atomicAdd(&statsO[0], a1);
        atomicAdd(&statsO[1], a2);
    }
}

// ---------------------------------------------------------------- readout: segment mean of gln(tbuf) -> 3x (dense+ln+tanh) -> dot
__global__ __launch_bounds__(256) void k_read(const float* __restrict__ tbuf,
                                              const float* __restrict__ stats,
                                              const float* __restrict__ gw,
                                              const float* __restrict__ gb,
                                              const int* __restrict__ offs,
                                              const float* __restrict__ Wp,
                                              const float* __restrict__ bp,
                                              const float* __restrict__ lnw,
                                              const float* __restrict__ lnb,
                                              const float* __restrict__ Wpo,
                                              const float* __restrict__ bpo,
                                              float* __restrict__ out) {
    int g = blockIdx.x;
    int t = threadIdx.x;
    int d = t & 31, pl = t >> 5;   // 8 point-lanes x 32 dims
    int s0 = offs[g], e0 = offs[g+1];
    float acc = 0.f;
    for (int n = s0 + pl; n < e0; n += 8) acc += tbuf[(size_t)n*DD + d];
    __shared__ float red[8][DD];
    red[pl][d] = acc;
    __syncthreads();
    __shared__ float sv[DD];
    if (t < DD) {
        float r = 0.f;
        #pragma unroll
        for (int q = 0; q < 8; q++) r += red[q][t];
        const float invM = 1.f / ((float)NPTS * DD);
        float m = stats[0] * invM;
        float var = stats[1] * invM - m*m;
        float inv = 1.f / (sqrtf(fmaxf(var, 0.f)) + EPSV);
        float cnt = (float)(e0 - s0);
        float mean = r / fmaxf(cnt, 1.f);
        sv[t] = (e0 > s0) ? (mean - m)*inv*gw[t] + gb[t] : 0.f;
    }
    __syncthreads();
    for (int j = 0; j < 3; j++) {
        float yv = 0.f;
        if (t < DD) {
            float y = bp[j*DD + t];
            #pragma unroll
            for (int i = 0; i < DD; i++) y += sv[i] * Wp[j*DD*DD + i*DD + t];
            float sum = y;
            #pragma unroll
            for (int o = 1; o < 32; o <<= 1) sum += __shfl_xor(sum, o);
            float m = sum * (1.f/DD);
            float c = y - m;
            float sq = c*c;
            #pragma unroll
            for (int o = 1; o < 32; o <<= 1) sq += __shfl_xor(sq, o);
            float var = sq * (1.f/DD);
            yv = tanh_fast(c / sqrtf(var + EPSV) * lnw[j*DD + t] + lnb[j*DD + t]);
        }
        __syncthreads();
        if (t < DD) sv[t] = yv;
        __syncthreads();
    }
    if (t < DD) {
        float p = sv[t] * Wpo[t];
        #pragma unroll
        for (int o = 1; o < 32; o <<= 1) p += __shfl_xor(p, o);
        if (t == 0) out[g] = p + bpo[0];
    }
}

extern "C" void kernel_launch(void* const* d_in, const int* in_sizes, int n_in,
                              void* d_out, int out_size, void* d_ws, size_t ws_size,
                              hipStream_t stream) {
    const float* x     = (const float*)d_in[0];
    const int*   batch = (const int*)  d_in[1];
    const float* Wi    = (const float*)d_in[2];
    const float* bi    = (const float*)d_in[3];
    const float* lni_w = (const float*)d_in[4];
    const float* lni_b = (const float*)d_in[5];
    const float* W_in  = (const float*)d_in[6];
    const float* b_in  = (const float*)d_in[7];
    const float* W_sc  = (const float*)d_in[8];
    const float* b_sc  = (const float*)d_in[9];
    const float* W_out = (const float*)d_in[10];
    const float* b_out = (const float*)d_in[11];
    const float* gln_w = (const float*)d_in[12];
    const float* gln_b = (const float*)d_in[13];
    const float* Wp    = (const float*)d_in[14];
    const float* bp    = (const float*)d_in[15];
    const float* lnp_w = (const float*)d_in[16];
    const float* lnp_b = (const float*)d_in[17];
    const float* Wpo   = (const float*)d_in[18];
    const float* bpo   = (const float*)d_in[19];
    float* out = (float*)d_out;

    float* ws    = (float*)d_ws;
    float* h     = ws;                              // NPTS*32
    float* tbuf  = h + (size_t)NPTS*DD;             // NPTS*32
    float* aggW  = tbuf + (size_t)NPTS*DD;          // NG*32
    float* stats = aggW + NG*DD;                    // 32
    float* Weff  = stats + 32;                      // 3*1024
    float* beff  = Weff + 3*DD*DD;                  // 96
    float* psum  = beff + 3*DD;                     // NG*SMAX*512
    float* pmax  = psum + (size_t)NG*SMAX*512;      // NG*SMAX*512
    int*   offs  = (int*)(pmax + (size_t)NG*SMAX*512); // NG+1

    k_init<<<1, 256, 0, stream>>>(batch, offs, stats);
    k_fold<<<3, 256, 0, stream>>>(W_in, b_in, W_out, b_out, Weff, beff);
    k_embed<<<(NPTS+255)/256, 256, 0, stream>>>(x, Wi, bi, lni_w, lni_b, h);

    for (int it = 0; it < 3; it++) {
        for (int j = 0; j < 3; j++) {
            int L = it*3 + j;
            const float* inb = L ? tbuf : h;
            const float* st  = L ? stats + 2*(L-1) : nullptr;
            int pj = (L + 2) % 3;
            const float* pgw = L ? gln_w + pj*DD : nullptr;
            const float* pgb = L ? gln_b + pj*DD : nullptr;
            k_A<<<NG*SMAX, 512, 0, stream>>>(
                inb, st, pgw, pgb,
                W_in + (size_t)j*DD*FF, b_in + j*FF, W_sc + (size_t)j*FF*AA, b_sc + j*AA,
                offs, psum, pmax);
            k_B<<<NG, 512, 0, stream>>>(
                psum, pmax, offs, W_out + (size_t)j*HINC*DD + (size_t)96*DD, beff + j*DD, aggW);
            k_C<<<(NPTS+63)/64, 512, 0, stream>>>(
                inb, st, pgw, pgb, aggW, batch, Weff + (size_t)j*DD*DD, tbuf, stats + 2*L);
        }
    }
    k_read<<<NG, 256, 0, stream>>>(tbuf, stats + 16, gln_w + 2*DD, gln_b + 2*DD,
                                   offs, Wp, bp, lnp_w, lnp_b, Wpo, bpo, out);
}